// Round 8
// baseline (82.606 us; speedup 1.0000x reference)
//
#include <hip/hip_runtime.h>
#include <cstddef>

namespace {
constexpr int TOK   = 206;
constexpr int NROWS = 256 * 682;        // 174592
constexpr int NPAIR = NROWS / 2;        // 87296
constexpr int GRID  = 1984;             // 1984*4 waves = 7936; 87296/7936 = 11 exactly
constexpr int NWAVE = GRID * 4;
constexpr int LROW2 = 310;              // doubles per LDS row; 2480B stride, 16B-aligned
constexpr int LDSF2 = 8 * LROW2 + 16;   // 8 rows (2/wave) + tail pad for q[9] reads
constexpr int NSLOT = 64;               // atomic spread slots
}

typedef float f32x4 __attribute__((ext_vector_type(4)));

__global__ __launch_bounds__(256) void cvl_main(
    const float* __restrict__ pred,
    const float* __restrict__ gt_acc,
    const float* __restrict__ gt_steer,
    const int*  __restrict__ gt_rev,
    double* __restrict__ ws)
{
    __shared__ alignas(16) double lds2[LDSF2];

    const int tid  = threadIdx.x;
    const int lane = tid & 63;
    const int wid  = tid >> 6;
    const int l32  = lane & 31;
    const int h    = lane >> 5;
    const int sr   = tid >> 5;           // == 2*wid + h : this lane's LDS row
    const int sc   = l32;
    double* myrow  = lds2 + sr * LROW2;  // wave-private slice; no cross-wave sharing

    float accS = 0.f, steerS = 0.f, revS = 0.f, cntS = 0.f;

    // burst-issue one pair's loads (no consumers attached)
    f32x4 v[5];
    double tl = 0.0;
    int   gtN; float gaN, gsN;
    auto load_pair = [&](int p) {
        const int row = 2 * p + h;
        const unsigned bb = (unsigned)row / 682u;        // magic-mul div
        // float offset (b*2048 + 3s)*206 == (3*row + 2*b)*206
        const float* base = pred + (size_t)(3u * (unsigned)row + 2u * bb) * TOK;
        #pragma unroll
        for (int k = 0; k < 4; ++k)
            v[k] = __builtin_nontemporal_load((const f32x4*)base + sc + 32 * k);
        if (sc < 26)                                     // 154 float4 = 4*32 + 26
            v[4] = __builtin_nontemporal_load((const f32x4*)base + sc + 128);
        if (sc == 31)                                    // row floats [616,618)
            tl = __builtin_nontemporal_load((const double*)(base + 616));
        gtN = gt_rev[row];
        gaN = gt_acc[row];
        gsN = gt_steer[row];
    };

    int p = blockIdx.x * 4 + wid;        // every wave runs exactly 11 pairs
    load_pair(p);

    while (p < NPAIR) {
        // land pair p into this wave's LDS slice (vmcnt wait here only)
        f32x4* lrow4 = (f32x4*)myrow;
        #pragma unroll
        for (int k = 0; k < 4; ++k) lrow4[sc + 32 * k] = v[k];
        if (sc < 26) lrow4[sc + 128] = v[4];
        if (sc == 31) myrow[308] = tl;
        const int   gt = gtN;
        const float ga = gaN;
        const float gs = gsN;

        // issue NEXT pair's loads now — in flight during compute below
        const int pn = p + NWAVE;
        if (pn < NPAIR) load_pair(pn);

        // ---- compute pair p from LDS (verified mapping, absmax 0.0) ------
        float2 q[10];
        #pragma unroll
        for (int k = 0; k < 10; ++k)
            q[k] = __builtin_bit_cast(float2, myrow[l32 + 32 * k]); // k=9 OOB lanes: pad, masked

        float aM = q[0].x; int aI = 2 * l32;
        if (q[0].y > aM) { aM = q[0].y; aI = 2 * l32 + 1; }
        #pragma unroll
        for (int k = 1; k <= 2; ++k) {
            const int t = 2 * (l32 + 32 * k);
            if (q[k].x > aM) { aM = q[k].x; aI = t; }
            if (q[k].y > aM) { aM = q[k].y; aI = t + 1; }
        }
        float sM = -INFINITY; int sI = 0;
        {   // k=3: acc if l32<7 else steer token 2*i2-206
            const int i2 = l32 + 96;
            if (l32 < 7) {
                if (q[3].x > aM) { aM = q[3].x; aI = 2 * i2; }
                if (q[3].y > aM) { aM = q[3].y; aI = 2 * i2 + 1; }
            } else {
                sM = q[3].x; sI = 2 * i2 - 206;
                if (q[3].y > sM) { sM = q[3].y; sI = 2 * i2 - 205; }
            }
        }
        #pragma unroll
        for (int k = 4; k <= 5; ++k) {   // steer tokens [50,178)
            const int st = 2 * (l32 + 32 * k) - 206;
            if (q[k].x > sM) { sM = q[k].x; sI = st; }
            if (q[k].y > sM) { sM = q[k].y; sI = st + 1; }
        }
        float lo = 0.f, hi = 0.f;
        {   // k=6: steer if l32<14 else rev (-> lo)
            if (l32 < 14) {
                const int st = 2 * (l32 + 192) - 206;
                if (q[6].x > sM) { sM = q[6].x; sI = st; }
                if (q[6].y > sM) { sM = q[6].y; sI = st + 1; }
            } else {
                lo += __expf(q[6].x) + __expf(q[6].y);
            }
        }
        lo += __expf(q[7].x) + __expf(q[7].y);           // rev tokens 36..99
        {   // k=8: rev tokens 2*l32+100 / +101
            const float ex = __expf(q[8].x), ey = __expf(q[8].y);
            if (l32 == 0) lo += ex; else hi += ex;
            hi += ey;
        }
        if (l32 < 21) hi += __expf(q[9].x) + __expf(q[9].y); // rev tokens 164..205

        #pragma unroll
        for (int off = 16; off >= 1; off >>= 1) {
            const float av = __shfl_xor(aM, off);
            const int   ai = __shfl_xor(aI, off);
            if (av > aM) { aM = av; aI = ai; }
            const float sv = __shfl_xor(sM, off);
            const int   si = __shfl_xor(sI, off);
            if (sv > sM) { sM = sv; sI = si; }
            lo += __shfl_xor(lo, off);
            hi += __shfl_xor(hi, off);
        }

        {   // per-row losses (uniform within each half-wave)
            const float Z    = lo + hi;
            const float pno  = lo / Z;
            const float prv  = hi / Z;
            const float ai_f = (float)aI;
            const float si_f = (float)sI;
            const float pa   = (ai_f > 101.f) ? (ai_f * (1.f / 101.f) - 1.f)
                                              : (1.f - ai_f * (1.f / 101.f));
            const float ps   = si_f * (1.f / 101.f) - 1.f;
            const float da   = pa - ga;
            const float dsv  = ps - gs;
            const float ada  = fabsf(da), ads = fabsf(dsv);
            accS   += (ada < 1.f) ? 0.5f * da * da   : ada - 0.5f;
            steerS += (ads < 1.f) ? 0.5f * dsv * dsv : ads - 0.5f;
            if (gt != -100) {
                const float m2 = fmaxf(pno, prv);
                revS += m2 + __logf(__expf(pno - m2) + __expf(prv - m2))
                        - ((gt == 0) ? pno : prv);
                cntS += 1.f;
            }
        }
        p = pn;
    }

    // ---- per-block tail: combine halves, waves, one atomic set per block -
    accS   += __shfl_xor(accS, 32);
    steerS += __shfl_xor(steerS, 32);
    revS   += __shfl_xor(revS, 32);
    cntS   += __shfl_xor(cntS, 32);

    __shared__ float red[4][4];
    if (lane == 0) {
        red[wid][0] = accS; red[wid][1] = steerS;
        red[wid][2] = revS; red[wid][3] = cntS;
    }
    __syncthreads();
    if (tid == 0) {
        double a = 0, st = 0, rr = 0, c = 0;
        for (int w = 0; w < 4; ++w) {
            a += red[w][0]; st += red[w][1]; rr += red[w][2]; c += red[w][3];
        }
        double* slot = ws + (size_t)(blockIdx.x & (NSLOT - 1)) * 4;
        atomicAdd(slot + 0, a);
        atomicAdd(slot + 1, st);
        atomicAdd(slot + 2, rr);
        atomicAdd(slot + 3, c);
    }
}

__global__ void cvl_init(double* __restrict__ ws) {
    const int i = blockIdx.x * blockDim.x + threadIdx.x;
    if (i < NSLOT * 4) ws[i] = 0.0;
}

__global__ void cvl_final(const double* __restrict__ ws, float* __restrict__ out) {
    const int t = threadIdx.x;           // 64 threads, one slot each
    double a = ws[4 * t], st = ws[4 * t + 1], r = ws[4 * t + 2], c = ws[4 * t + 3];
    #pragma unroll
    for (int off = 32; off >= 1; off >>= 1) {
        a  += __shfl_xor(a,  off);
        st += __shfl_xor(st, off);
        r  += __shfl_xor(r,  off);
        c  += __shfl_xor(c,  off);
    }
    if (t == 0) {
        const double n = (double)NROWS;
        out[0] = (float)(a / n + st / n);
        out[1] = (float)(r / fmax(c, 1.0));
    }
}

extern "C" void kernel_launch(void* const* d_in, const int* in_sizes, int n_in,
                              void* d_out, int out_size, void* d_ws, size_t ws_size,
                              hipStream_t stream) {
    const float* pred     = (const float*)d_in[0];
    const float* gt_acc   = (const float*)d_in[1];
    const float* gt_steer = (const float*)d_in[2];
    const int*   gt_rev   = (const int*)d_in[3];
    double* ws  = (double*)d_ws;
    float*  out = (float*)d_out;

    cvl_init<<<1, 256, 0, stream>>>(ws);
    cvl_main<<<GRID, 256, 0, stream>>>(pred, gt_acc, gt_steer, gt_rev, ws);
    cvl_final<<<1, 64, 0, stream>>>(ws, out);
}

// Round 9
// 75.837 us; speedup vs baseline: 1.0893x; 1.0893x over previous
//
#include <hip/hip_runtime.h>
#include <cstddef>

namespace {
constexpr int TOK   = 206;
constexpr int NROWS = 256 * 682;        // 174592
constexpr int NPAIR = NROWS / 2;        // 87296
constexpr int GRID  = 1984;             // 1984*4 waves = 7936; 87296/7936 = 11 exactly
constexpr int NWAVE = GRID * 4;
constexpr int LROW2 = 310;              // doubles per LDS row; 2480B stride, 16B-aligned
constexpr int LDSF2 = 8 * LROW2 + 16;   // 8 rows (2/wave) + tail pad for q[9] reads
}

typedef float f32x4 __attribute__((ext_vector_type(4)));

__global__ __launch_bounds__(256) void cvl_main(
    const float* __restrict__ pred,
    const float* __restrict__ gt_acc,
    const float* __restrict__ gt_steer,
    const int*  __restrict__ gt_rev,
    f32x4* __restrict__ ws)
{
    __shared__ alignas(16) double lds2[LDSF2];

    const int tid  = threadIdx.x;
    const int lane = tid & 63;
    const int wid  = tid >> 6;
    const int l32  = lane & 31;
    const int h    = lane >> 5;
    const int sr   = tid >> 5;           // == 2*wid + h : this lane's LDS row
    const int sc   = l32;
    double* myrow  = lds2 + sr * LROW2;  // wave-private slice; no cross-wave sharing

    float accS = 0.f, steerS = 0.f, revS = 0.f, cntS = 0.f;

    // burst-issue one pair's loads (no consumers attached)
    f32x4 v[5];
    double tl = 0.0;
    int   gtN; float gaN, gsN;
    auto load_pair = [&](int p) {
        const int row = 2 * p + h;
        const unsigned bb = (unsigned)row / 682u;        // magic-mul div
        // float offset (b*2048 + 3s)*206 == (3*row + 2*b)*206
        const float* base = pred + (size_t)(3u * (unsigned)row + 2u * bb) * TOK;
        #pragma unroll
        for (int k = 0; k < 4; ++k)
            v[k] = __builtin_nontemporal_load((const f32x4*)base + sc + 32 * k);
        if (sc < 26)                                     // 154 float4 = 4*32 + 26
            v[4] = __builtin_nontemporal_load((const f32x4*)base + sc + 128);
        if (sc == 31)                                    // row floats [616,618)
            tl = __builtin_nontemporal_load((const double*)(base + 616));
        gtN = gt_rev[row];
        gaN = gt_acc[row];
        gsN = gt_steer[row];
    };

    int p = blockIdx.x * 4 + wid;        // every wave runs exactly 11 pairs
    load_pair(p);

    while (p < NPAIR) {
        // land pair p into this wave's LDS slice (vmcnt wait here only)
        f32x4* lrow4 = (f32x4*)myrow;
        #pragma unroll
        for (int k = 0; k < 4; ++k) lrow4[sc + 32 * k] = v[k];
        if (sc < 26) lrow4[sc + 128] = v[4];
        if (sc == 31) myrow[308] = tl;
        const int   gt = gtN;
        const float ga = gaN;
        const float gs = gsN;

        // issue NEXT pair's loads now — in flight during compute below
        const int pn = p + NWAVE;
        if (pn < NPAIR) load_pair(pn);

        // ---- compute pair p from LDS (verified mapping, absmax 0.0) ------
        float2 q[10];
        #pragma unroll
        for (int k = 0; k < 10; ++k)
            q[k] = __builtin_bit_cast(float2, myrow[l32 + 32 * k]); // k=9 OOB lanes: pad, masked

        float aM = q[0].x; int aI = 2 * l32;
        if (q[0].y > aM) { aM = q[0].y; aI = 2 * l32 + 1; }
        #pragma unroll
        for (int k = 1; k <= 2; ++k) {
            const int t = 2 * (l32 + 32 * k);
            if (q[k].x > aM) { aM = q[k].x; aI = t; }
            if (q[k].y > aM) { aM = q[k].y; aI = t + 1; }
        }
        float sM = -INFINITY; int sI = 0;
        {   // k=3: acc if l32<7 else steer token 2*i2-206
            const int i2 = l32 + 96;
            if (l32 < 7) {
                if (q[3].x > aM) { aM = q[3].x; aI = 2 * i2; }
                if (q[3].y > aM) { aM = q[3].y; aI = 2 * i2 + 1; }
            } else {
                sM = q[3].x; sI = 2 * i2 - 206;
                if (q[3].y > sM) { sM = q[3].y; sI = 2 * i2 - 205; }
            }
        }
        #pragma unroll
        for (int k = 4; k <= 5; ++k) {   // steer tokens [50,178)
            const int st = 2 * (l32 + 32 * k) - 206;
            if (q[k].x > sM) { sM = q[k].x; sI = st; }
            if (q[k].y > sM) { sM = q[k].y; sI = st + 1; }
        }
        float lo = 0.f, hi = 0.f;
        {   // k=6: steer if l32<14 else rev (-> lo)
            if (l32 < 14) {
                const int st = 2 * (l32 + 192) - 206;
                if (q[6].x > sM) { sM = q[6].x; sI = st; }
                if (q[6].y > sM) { sM = q[6].y; sI = st + 1; }
            } else {
                lo += __expf(q[6].x) + __expf(q[6].y);
            }
        }
        lo += __expf(q[7].x) + __expf(q[7].y);           // rev tokens 36..99
        {   // k=8: rev tokens 2*l32+100 / +101
            const float ex = __expf(q[8].x), ey = __expf(q[8].y);
            if (l32 == 0) lo += ex; else hi += ex;
            hi += ey;
        }
        if (l32 < 21) hi += __expf(q[9].x) + __expf(q[9].y); // rev tokens 164..205

        #pragma unroll
        for (int off = 16; off >= 1; off >>= 1) {
            const float av = __shfl_xor(aM, off);
            const int   ai = __shfl_xor(aI, off);
            if (av > aM) { aM = av; aI = ai; }
            const float sv = __shfl_xor(sM, off);
            const int   si = __shfl_xor(sI, off);
            if (sv > sM) { sM = sv; sI = si; }
            lo += __shfl_xor(lo, off);
            hi += __shfl_xor(hi, off);
        }

        {   // per-row losses (uniform within each half-wave)
            const float Z    = lo + hi;
            const float pno  = lo / Z;
            const float prv  = hi / Z;
            const float ai_f = (float)aI;
            const float si_f = (float)sI;
            const float pa   = (ai_f > 101.f) ? (ai_f * (1.f / 101.f) - 1.f)
                                              : (1.f - ai_f * (1.f / 101.f));
            const float ps   = si_f * (1.f / 101.f) - 1.f;
            const float da   = pa - ga;
            const float dsv  = ps - gs;
            const float ada  = fabsf(da), ads = fabsf(dsv);
            accS   += (ada < 1.f) ? 0.5f * da * da   : ada - 0.5f;
            steerS += (ads < 1.f) ? 0.5f * dsv * dsv : ads - 0.5f;
            if (gt != -100) {
                const float m2 = fmaxf(pno, prv);
                revS += m2 + __logf(__expf(pno - m2) + __expf(prv - m2))
                        - ((gt == 0) ? pno : prv);
                cntS += 1.f;
            }
        }
        p = pn;
    }

    // ---- per-block tail: combine halves & waves, ONE plain store/block ---
    accS   += __shfl_xor(accS, 32);
    steerS += __shfl_xor(steerS, 32);
    revS   += __shfl_xor(revS, 32);
    cntS   += __shfl_xor(cntS, 32);

    __shared__ float red[4][4];
    if (lane == 0) {
        red[wid][0] = accS; red[wid][1] = steerS;
        red[wid][2] = revS; red[wid][3] = cntS;
    }
    __syncthreads();
    if (tid == 0) {
        float a = 0.f, st = 0.f, rr = 0.f, c = 0.f;
        for (int w = 0; w < 4; ++w) {
            a += red[w][0]; st += red[w][1]; rr += red[w][2]; c += red[w][3];
        }
        ws[blockIdx.x] = (f32x4){a, st, rr, c};   // unconditional every call: poison-safe
    }
}

__global__ __launch_bounds__(256) void cvl_final(
    const f32x4* __restrict__ ws, float* __restrict__ out)
{
    const int tid  = threadIdx.x;
    const int lane = tid & 63;
    const int wid  = tid >> 6;

    double a = 0.0, s = 0.0, r = 0.0, c = 0.0;
    for (int i = tid; i < GRID; i += 256) {
        const f32x4 pv = ws[i];
        a += pv.x; s += pv.y; r += pv.z; c += pv.w;
    }
    #pragma unroll
    for (int off = 32; off >= 1; off >>= 1) {
        a += __shfl_xor(a, off);
        s += __shfl_xor(s, off);
        r += __shfl_xor(r, off);
        c += __shfl_xor(c, off);
    }
    __shared__ double sm[4][4];
    if (lane == 0) { sm[wid][0] = a; sm[wid][1] = s; sm[wid][2] = r; sm[wid][3] = c; }
    __syncthreads();
    if (tid == 0) {
        double A = 0, S = 0, Rr = 0, C = 0;
        for (int w = 0; w < 4; ++w) {
            A += sm[w][0]; S += sm[w][1]; Rr += sm[w][2]; C += sm[w][3];
        }
        const double n = (double)NROWS;
        out[0] = (float)(A / n + S / n);
        out[1] = (float)(Rr / fmax(C, 1.0));
    }
}

extern "C" void kernel_launch(void* const* d_in, const int* in_sizes, int n_in,
                              void* d_out, int out_size, void* d_ws, size_t ws_size,
                              hipStream_t stream) {
    const float* pred     = (const float*)d_in[0];
    const float* gt_acc   = (const float*)d_in[1];
    const float* gt_steer = (const float*)d_in[2];
    const int*   gt_rev   = (const int*)d_in[3];
    f32x4* ws  = (f32x4*)d_ws;
    float* out = (float*)d_out;

    cvl_main<<<GRID, 256, 0, stream>>>(pred, gt_acc, gt_steer, gt_rev, ws);
    cvl_final<<<1, 256, 0, stream>>>(ws, out);
}

// Round 10
// 75.513 us; speedup vs baseline: 1.0939x; 1.0043x over previous
//
#include <hip/hip_runtime.h>
#include <cstddef>

namespace {
constexpr int TOK   = 206;
constexpr int NROWS = 256 * 682;        // 174592
constexpr int NPAIR = NROWS / 2;        // 87296
constexpr int GRID  = 992;              // 992*4 = 3968 waves; 87296/3968 = 22 exactly
constexpr int NWAVE = GRID * 4;
constexpr int LROW2 = 310;              // doubles per LDS row; 2480B stride, 16B-aligned
constexpr int LDSF2 = 8 * LROW2 + 16;   // 8 rows (2/wave) + tail pad for q[9] reads
}

typedef float f32x4 __attribute__((ext_vector_type(4)));

__global__ __launch_bounds__(256) void cvl_main(
    const float* __restrict__ pred,
    const float* __restrict__ gt_acc,
    const float* __restrict__ gt_steer,
    const int*  __restrict__ gt_rev,
    f32x4* __restrict__ ws)
{
    __shared__ alignas(16) double lds2[LDSF2];

    const int tid  = threadIdx.x;
    const int lane = tid & 63;
    const int wid  = tid >> 6;
    const int l32  = lane & 31;
    const int h    = lane >> 5;
    const int sr   = tid >> 5;           // == 2*wid + h : this lane's LDS row
    const int sc   = l32;
    double* myrow  = lds2 + sr * LROW2;  // wave-private slice; no cross-wave sharing

    float accS = 0.f, steerS = 0.f, revS = 0.f, cntS = 0.f;

    // burst-issue one pair's loads (no consumers attached)
    f32x4 v[5];
    double tl = 0.0;
    int   gtN; float gaN, gsN;
    auto load_pair = [&](int p) {
        const int row = 2 * p + h;
        const unsigned bb = (unsigned)row / 682u;        // magic-mul div
        // float offset (b*2048 + 3s)*206 == (3*row + 2*b)*206
        const float* base = pred + (size_t)(3u * (unsigned)row + 2u * bb) * TOK;
        #pragma unroll
        for (int k = 0; k < 4; ++k)
            v[k] = __builtin_nontemporal_load((const f32x4*)base + sc + 32 * k);
        if (sc < 26)                                     // 154 float4 = 4*32 + 26
            v[4] = __builtin_nontemporal_load((const f32x4*)base + sc + 128);
        if (sc == 31)                                    // row floats [616,618)
            tl = __builtin_nontemporal_load((const double*)(base + 616));
        gtN = gt_rev[row];
        gaN = gt_acc[row];
        gsN = gt_steer[row];
    };

    int p = blockIdx.x * 4 + wid;        // every wave runs exactly 22 pairs
    load_pair(p);

    while (p < NPAIR) {
        // land pair p into this wave's LDS slice (vmcnt wait here only)
        f32x4* lrow4 = (f32x4*)myrow;
        #pragma unroll
        for (int k = 0; k < 4; ++k) lrow4[sc + 32 * k] = v[k];
        if (sc < 26) lrow4[sc + 128] = v[4];
        if (sc == 31) myrow[308] = tl;
        const int   gt = gtN;
        const float ga = gaN;
        const float gs = gsN;

        // issue NEXT pair's loads now — in flight during compute below
        const int pn = p + NWAVE;
        if (pn < NPAIR) load_pair(pn);

        // ---- compute pair p from LDS (verified mapping, absmax 0.0) ------
        float2 q[10];
        #pragma unroll
        for (int k = 0; k < 10; ++k)
            q[k] = __builtin_bit_cast(float2, myrow[l32 + 32 * k]); // k=9 OOB lanes: pad, masked

        float aM = q[0].x; int aI = 2 * l32;
        if (q[0].y > aM) { aM = q[0].y; aI = 2 * l32 + 1; }
        #pragma unroll
        for (int k = 1; k <= 2; ++k) {
            const int t = 2 * (l32 + 32 * k);
            if (q[k].x > aM) { aM = q[k].x; aI = t; }
            if (q[k].y > aM) { aM = q[k].y; aI = t + 1; }
        }
        float sM = -INFINITY; int sI = 0;
        {   // k=3: acc if l32<7 else steer token 2*i2-206
            const int i2 = l32 + 96;
            if (l32 < 7) {
                if (q[3].x > aM) { aM = q[3].x; aI = 2 * i2; }
                if (q[3].y > aM) { aM = q[3].y; aI = 2 * i2 + 1; }
            } else {
                sM = q[3].x; sI = 2 * i2 - 206;
                if (q[3].y > sM) { sM = q[3].y; sI = 2 * i2 - 205; }
            }
        }
        #pragma unroll
        for (int k = 4; k <= 5; ++k) {   // steer tokens [50,178)
            const int st = 2 * (l32 + 32 * k) - 206;
            if (q[k].x > sM) { sM = q[k].x; sI = st; }
            if (q[k].y > sM) { sM = q[k].y; sI = st + 1; }
        }
        float lo = 0.f, hi = 0.f;
        {   // k=6: steer if l32<14 else rev (-> lo)
            if (l32 < 14) {
                const int st = 2 * (l32 + 192) - 206;
                if (q[6].x > sM) { sM = q[6].x; sI = st; }
                if (q[6].y > sM) { sM = q[6].y; sI = st + 1; }
            } else {
                lo += __expf(q[6].x) + __expf(q[6].y);
            }
        }
        lo += __expf(q[7].x) + __expf(q[7].y);           // rev tokens 36..99
        {   // k=8: rev tokens 2*l32+100 / +101
            const float ex = __expf(q[8].x), ey = __expf(q[8].y);
            if (l32 == 0) lo += ex; else hi += ex;
            hi += ey;
        }
        if (l32 < 21) hi += __expf(q[9].x) + __expf(q[9].y); // rev tokens 164..205

        #pragma unroll
        for (int off = 16; off >= 1; off >>= 1) {
            const float av = __shfl_xor(aM, off);
            const int   ai = __shfl_xor(aI, off);
            if (av > aM) { aM = av; aI = ai; }
            const float sv = __shfl_xor(sM, off);
            const int   si = __shfl_xor(sI, off);
            if (sv > sM) { sM = sv; sI = si; }
            lo += __shfl_xor(lo, off);
            hi += __shfl_xor(hi, off);
        }

        {   // per-row losses (uniform within each half-wave)
            const float Z    = lo + hi;
            const float pno  = lo / Z;
            const float prv  = hi / Z;
            const float ai_f = (float)aI;
            const float si_f = (float)sI;
            const float pa   = (ai_f > 101.f) ? (ai_f * (1.f / 101.f) - 1.f)
                                              : (1.f - ai_f * (1.f / 101.f));
            const float ps   = si_f * (1.f / 101.f) - 1.f;
            const float da   = pa - ga;
            const float dsv  = ps - gs;
            const float ada  = fabsf(da), ads = fabsf(dsv);
            accS   += (ada < 1.f) ? 0.5f * da * da   : ada - 0.5f;
            steerS += (ads < 1.f) ? 0.5f * dsv * dsv : ads - 0.5f;
            if (gt != -100) {
                const float m2 = fmaxf(pno, prv);
                revS += m2 + __logf(__expf(pno - m2) + __expf(prv - m2))
                        - ((gt == 0) ? pno : prv);
                cntS += 1.f;
            }
        }
        p = pn;
    }

    // ---- per-block tail: combine halves & waves, ONE plain store/block ---
    accS   += __shfl_xor(accS, 32);
    steerS += __shfl_xor(steerS, 32);
    revS   += __shfl_xor(revS, 32);
    cntS   += __shfl_xor(cntS, 32);

    __shared__ float red[4][4];
    if (lane == 0) {
        red[wid][0] = accS; red[wid][1] = steerS;
        red[wid][2] = revS; red[wid][3] = cntS;
    }
    __syncthreads();
    if (tid == 0) {
        float a = 0.f, st = 0.f, rr = 0.f, c = 0.f;
        for (int w = 0; w < 4; ++w) {
            a += red[w][0]; st += red[w][1]; rr += red[w][2]; c += red[w][3];
        }
        ws[blockIdx.x] = (f32x4){a, st, rr, c};   // unconditional every call: poison-safe
    }
}

__global__ __launch_bounds__(256) void cvl_final(
    const f32x4* __restrict__ ws, float* __restrict__ out)
{
    const int tid  = threadIdx.x;
    const int lane = tid & 63;
    const int wid  = tid >> 6;

    double a = 0.0, s = 0.0, r = 0.0, c = 0.0;
    for (int i = tid; i < GRID; i += 256) {
        const f32x4 pv = ws[i];
        a += pv.x; s += pv.y; r += pv.z; c += pv.w;
    }
    #pragma unroll
    for (int off = 32; off >= 1; off >>= 1) {
        a += __shfl_xor(a, off);
        s += __shfl_xor(s, off);
        r += __shfl_xor(r, off);
        c += __shfl_xor(c, off);
    }
    __shared__ double sm[4][4];
    if (lane == 0) { sm[wid][0] = a; sm[wid][1] = s; sm[wid][2] = r; sm[wid][3] = c; }
    __syncthreads();
    if (tid == 0) {
        double A = 0, S = 0, Rr = 0, C = 0;
        for (int w = 0; w < 4; ++w) {
            A += sm[w][0]; S += sm[w][1]; Rr += sm[w][2]; C += sm[w][3];
        }
        const double n = (double)NROWS;
        out[0] = (float)(A / n + S / n);
        out[1] = (float)(Rr / fmax(C, 1.0));
    }
}

extern "C" void kernel_launch(void* const* d_in, const int* in_sizes, int n_in,
                              void* d_out, int out_size, void* d_ws, size_t ws_size,
                              hipStream_t stream) {
    const float* pred     = (const float*)d_in[0];
    const float* gt_acc   = (const float*)d_in[1];
    const float* gt_steer = (const float*)d_in[2];
    const int*   gt_rev   = (const int*)d_in[3];
    f32x4* ws  = (f32x4*)d_ws;
    float* out = (float*)d_out;

    cvl_main<<<GRID, 256, 0, stream>>>(pred, gt_acc, gt_steer, gt_rev, ws);
    cvl_final<<<1, 256, 0, stream>>>(ws, out);
}